// Round 8
// baseline (144.594 us; speedup 1.0000x reference)
//
#include <hip/hip_runtime.h>

#define BB 32
#define NN 1024
#define FIN 64
#define HH 24
#define SQRT_LOG2E 1.2011224087864498f

typedef __attribute__((ext_vector_type(8))) short short8;
typedef __attribute__((ext_vector_type(4))) float floatx4;

static __device__ inline unsigned short bf16_rtne(float f) {
    unsigned u = __float_as_uint(f);
    unsigned r = u + 0x7FFFu + ((u >> 16) & 1u);
    return (unsigned short)(r >> 16);
}

// ---------------- kernel 1: Z = relu(xt@W+b) * SQRT_LOG2E, split hi/lo bf16 ----------------
// Zhl[b][n] = 64 ushorts: [0..23] hi bf16, [24..31] 0, [32..55] lo bf16, [56..63] 0
__global__ void k_z(const float* __restrict__ xt, const float* __restrict__ W,
                    const float* __restrict__ bias, unsigned short* __restrict__ Zhl) {
    __shared__ float Wl[FIN * HH];
    int t = threadIdx.x;
    for (int i = t; i < FIN * HH; i += 256) Wl[i] = W[i];
    __syncthreads();

    int row = blockIdx.x * 256 + t;      // b*N + n

    const float* xr = xt + (size_t)row * FIN;
    float x[FIN];
    #pragma unroll
    for (int k4 = 0; k4 < FIN / 4; ++k4) {
        float4 v = reinterpret_cast<const float4*>(xr)[k4];
        x[4 * k4 + 0] = v.x; x[4 * k4 + 1] = v.y;
        x[4 * k4 + 2] = v.z; x[4 * k4 + 3] = v.w;
    }

    unsigned short u[64];
    #pragma unroll
    for (int i = 0; i < 64; ++i) u[i] = 0;

    #pragma unroll
    for (int hg = 0; hg < HH / 4; ++hg) {
        float4 acc = reinterpret_cast<const float4*>(bias)[hg];
        #pragma unroll
        for (int k = 0; k < FIN; ++k) {
            float4 w = *reinterpret_cast<const float4*>(&Wl[k * HH + hg * 4]);
            acc.x += x[k] * w.x; acc.y += x[k] * w.y;
            acc.z += x[k] * w.z; acc.w += x[k] * w.w;
        }
        float zs[4] = { fmaxf(acc.x, 0.f) * SQRT_LOG2E, fmaxf(acc.y, 0.f) * SQRT_LOG2E,
                        fmaxf(acc.z, 0.f) * SQRT_LOG2E, fmaxf(acc.w, 0.f) * SQRT_LOG2E };
        #pragma unroll
        for (int j = 0; j < 4; ++j) {
            int h = hg * 4 + j;
            unsigned short hb = bf16_rtne(zs[j]);
            float hf = __uint_as_float((unsigned)hb << 16);
            u[h] = hb;
            u[32 + h] = bf16_rtne(zs[j] - hf);
        }
    }

    unsigned short* dst = Zhl + ((size_t)row << 6);
    #pragma unroll
    for (int i = 0; i < 8; ++i)
        reinterpret_cast<uint4*>(dst)[i] = *reinterpret_cast<const uint4*>(&u[i * 8]);
}

// Common geometry (pair-sweep kernels, NO LDS / NO BARRIERS):
//  grid (16 n-blocks, 4 m-splits, 32 b); block 256 = 4 waves; wave owns 16 n (B operand, regs);
//  m-window 256 rows; A-frags read straight from global Zhl (L1/L2-hot, 32KB window):
//  per tile, 64 lanes read 16 rows x 64B = 16 fully-consumed lines per dwordx4 instr.
//  MFMA 16x16x32 bf16, A = m-rows, B = n-frag, 3x: mh*nh + mh*nl + ml*nh.
//  C layout: lane holds n = n0w + (lane&15), m = tt*16 + (lane>>4)*4 + k  (4 consecutive m).

#define LOAD_N_FRAGS()                                                                   \
    const unsigned short* nrow_ = Zhl + (((size_t)b * NN + n0w + r15) << 6) + (g << 3);  \
    short8 nh = *reinterpret_cast<const short8*>(nrow_);                                 \
    short8 nl = *reinterpret_cast<const short8*>(nrow_ + 32);

#define MFMA_TILE_G(tt)                                                                  \
    const unsigned short* ap_ =                                                          \
        Zhl + (((size_t)b * NN + mbase + (tt) * 16 + r15) << 6) + (g << 3);              \
    short8 mh = *reinterpret_cast<const short8*>(ap_);                                   \
    short8 ml = *reinterpret_cast<const short8*>(ap_ + 32);                              \
    floatx4 acc = {0.f, 0.f, 0.f, 0.f};                                                 \
    acc = __builtin_amdgcn_mfma_f32_16x16x32_bf16(mh, nh, acc, 0, 0, 0);                 \
    acc = __builtin_amdgcn_mfma_f32_16x16x32_bf16(mh, nl, acc, 0, 0, 0);                 \
    acc = __builtin_amdgcn_mfma_f32_16x16x32_bf16(ml, nh, acc, 0, 0, 0);

// ---------------- kernel 2: partial row sums  ps[ms][b][n] = sum_{m in window} exp2(a) ----
__global__ __launch_bounds__(256) void k_rowsum(
        const unsigned short* __restrict__ Zhl, float* __restrict__ ps) {
    int t = threadIdx.x, lane = t & 63;
    int r15 = lane & 15, g = lane >> 4;
    int b = blockIdx.z;
    int n0w = blockIdx.x * 64 + (t >> 6) * 16;
    int mbase = blockIdx.y * 256;

    LOAD_N_FRAGS();

    float s = 0.f;
    #pragma unroll 4
    for (int tt = 0; tt < 16; ++tt) {
        MFMA_TILE_G(tt);
        s += __builtin_amdgcn_exp2f(acc[0]) + __builtin_amdgcn_exp2f(acc[1])
           + __builtin_amdgcn_exp2f(acc[2]) + __builtin_amdgcn_exp2f(acc[3]);
    }

    s += __shfl_xor(s, 16, 64);
    s += __shfl_xor(s, 32, 64);
    if (g == 0)
        ps[((size_t)blockIdx.y * BB + b) * NN + n0w + r15] = s;
}

// ---------------- kernel 2b: rinv = 1 / (sum of partials) ----------------
__global__ void k_sfin(const float* __restrict__ ps, float* __restrict__ rinv) {
    int i = blockIdx.x * 256 + threadIdx.x;
    rinv[i] = 1.0f / (ps[i] + ps[32768 + i] + ps[65536 + i] + ps[98304 + i]);
}

// ---------------- kernel 3: partial col sums  pc[ms][b][n] = sum_m exp2(a)*rinv_m --------
__global__ __launch_bounds__(256) void k_colsum(
        const unsigned short* __restrict__ Zhl, const float* __restrict__ rinv,
        float* __restrict__ pc) {
    int t = threadIdx.x, lane = t & 63;
    int r15 = lane & 15, g = lane >> 4;
    int b = blockIdx.z;
    int n0w = blockIdx.x * 64 + (t >> 6) * 16;
    int mbase = blockIdx.y * 256;

    LOAD_N_FRAGS();

    float c = 0.f;
    #pragma unroll 4
    for (int tt = 0; tt < 16; ++tt) {
        MFMA_TILE_G(tt);
        float4 rm4 = *reinterpret_cast<const float4*>(
            &rinv[(size_t)b * NN + mbase + tt * 16 + g * 4]);
        c += __builtin_amdgcn_exp2f(acc[0]) * rm4.x + __builtin_amdgcn_exp2f(acc[1]) * rm4.y
           + __builtin_amdgcn_exp2f(acc[2]) * rm4.z + __builtin_amdgcn_exp2f(acc[3]) * rm4.w;
    }

    c += __shfl_xor(c, 16, 64);
    c += __shfl_xor(c, 32, 64);
    if (g == 0)
        pc[((size_t)blockIdx.y * BB + b) * NN + n0w + r15] = c;
}

// ---------------- kernel 3b: dinv = rsqrt(1.5 + 0.5 * colsum) ----------------
__global__ void k_cfin(const float* __restrict__ pc, float* __restrict__ dinv) {
    int i = blockIdx.x * 256 + threadIdx.x;
    dinv[i] = rsqrtf(1.5f + 0.5f * (pc[i] + pc[32768 + i] + pc[65536 + i] + pc[98304 + i]));
}

// ---------------- kernel 4: out = (exp2(a)*0.5*(rinv_n + rinv_m) + diag) * dvn * dvm -----
__global__ __launch_bounds__(256) void k_out(
        const unsigned short* __restrict__ Zhl, const float* __restrict__ rinv,
        const float* __restrict__ dinv, float* __restrict__ out) {
    int t = threadIdx.x, lane = t & 63;
    int r15 = lane & 15, g = lane >> 4;
    int b = blockIdx.z;
    int n0w = blockIdx.x * 64 + (t >> 6) * 16;
    int mbase = blockIdx.y * 256;

    int n = n0w + r15;
    float en  = 0.5f * rinv[(size_t)b * NN + n];
    float dvn = dinv[(size_t)b * NN + n];

    LOAD_N_FRAGS();

    float* orow = out + ((size_t)b * NN + n) * NN;

    #pragma unroll 4
    for (int tt = 0; tt < 16; ++tt) {
        MFMA_TILE_G(tt);
        int mg = mbase + tt * 16 + g * 4;
        float4 rm4 = *reinterpret_cast<const float4*>(&rinv[(size_t)b * NN + mg]);
        float4 dv4 = *reinterpret_cast<const float4*>(&dinv[(size_t)b * NN + mg]);
        float4 o;
        float w0 = dvn * dv4.x, w1 = dvn * dv4.y, w2 = dvn * dv4.z, w3 = dvn * dv4.w;
        o.x = __builtin_amdgcn_exp2f(acc[0]) * (en + 0.5f * rm4.x) * w0;
        o.y = __builtin_amdgcn_exp2f(acc[1]) * (en + 0.5f * rm4.y) * w1;
        o.z = __builtin_amdgcn_exp2f(acc[2]) * (en + 0.5f * rm4.z) * w2;
        o.w = __builtin_amdgcn_exp2f(acc[3]) * (en + 0.5f * rm4.w) * w3;
        if (n == mg + 0) o.x += w0;
        if (n == mg + 1) o.y += w1;
        if (n == mg + 2) o.z += w2;
        if (n == mg + 3) o.w += w3;
        *reinterpret_cast<float4*>(orow + mg) = o;
    }
}

extern "C" void kernel_launch(void* const* d_in, const int* in_sizes, int n_in,
                              void* d_out, int out_size, void* d_ws, size_t ws_size,
                              hipStream_t stream) {
    const float* xt   = (const float*)d_in[0];
    const float* W    = (const float*)d_in[1];
    const float* bias = (const float*)d_in[2];
    float* out = (float*)d_out;
    float* ws  = (float*)d_ws;

    unsigned short* Zhl = (unsigned short*)ws;          // 32*1024*64 u16 = 1,048,576 floats
    float* ps   = ws + 1048576;                         // [4][32][1024] = 131072
    float* pc   = ws + 1048576 + 131072;                // [4][32][1024] = 131072
    float* rinv = ws + 1048576 + 262144;                // 32768
    float* dinv = ws + 1048576 + 294912;                // 32768

    k_z<<<dim3(BB * NN / 256), dim3(256), 0, stream>>>(xt, W, bias, Zhl);
    k_rowsum<<<dim3(16, 4, BB), dim3(256), 0, stream>>>(Zhl, ps);
    k_sfin<<<dim3(128), dim3(256), 0, stream>>>(ps, rinv);
    k_colsum<<<dim3(16, 4, BB), dim3(256), 0, stream>>>(Zhl, rinv, pc);
    k_cfin<<<dim3(128), dim3(256), 0, stream>>>(pc, dinv);
    k_out<<<dim3(16, 4, BB), dim3(256), 0, stream>>>(Zhl, rinv, dinv, out);
}

// Round 9
// 97.097 us; speedup vs baseline: 1.4892x; 1.4892x over previous
//
#include <hip/hip_runtime.h>

#define BB 32
#define NN 1024
#define FIN 64
#define HH 24
#define SQRT_LOG2E 1.2011224087864498f

typedef __attribute__((ext_vector_type(8))) short short8;
typedef __attribute__((ext_vector_type(4))) float floatx4;

static __device__ inline unsigned short bf16_rtne(float f) {
    unsigned u = __float_as_uint(f);
    unsigned r = u + 0x7FFFu + ((u >> 16) & 1u);
    return (unsigned short)(r >> 16);
}

// ---------------- kernel 1: Z = relu(xt@W+b) * SQRT_LOG2E, split hi/lo bf16 ----------------
// Zhl[b][n] = 64 ushorts: [0..23] hi bf16, [24..31] 0, [32..55] lo bf16, [56..63] 0
__global__ void k_z(const float* __restrict__ xt, const float* __restrict__ W,
                    const float* __restrict__ bias, unsigned short* __restrict__ Zhl) {
    __shared__ float Wl[FIN * HH];
    int t = threadIdx.x;
    for (int i = t; i < FIN * HH; i += 256) Wl[i] = W[i];
    __syncthreads();

    int row = blockIdx.x * 256 + t;      // b*N + n

    const float* xr = xt + (size_t)row * FIN;
    float x[FIN];
    #pragma unroll
    for (int k4 = 0; k4 < FIN / 4; ++k4) {
        float4 v = reinterpret_cast<const float4*>(xr)[k4];
        x[4 * k4 + 0] = v.x; x[4 * k4 + 1] = v.y;
        x[4 * k4 + 2] = v.z; x[4 * k4 + 3] = v.w;
    }

    unsigned short u[64];
    #pragma unroll
    for (int i = 0; i < 64; ++i) u[i] = 0;

    #pragma unroll
    for (int hg = 0; hg < HH / 4; ++hg) {
        float4 acc = reinterpret_cast<const float4*>(bias)[hg];
        #pragma unroll
        for (int k = 0; k < FIN; ++k) {
            float4 w = *reinterpret_cast<const float4*>(&Wl[k * HH + hg * 4]);
            acc.x += x[k] * w.x; acc.y += x[k] * w.y;
            acc.z += x[k] * w.z; acc.w += x[k] * w.w;
        }
        float zs[4] = { fmaxf(acc.x, 0.f) * SQRT_LOG2E, fmaxf(acc.y, 0.f) * SQRT_LOG2E,
                        fmaxf(acc.z, 0.f) * SQRT_LOG2E, fmaxf(acc.w, 0.f) * SQRT_LOG2E };
        #pragma unroll
        for (int j = 0; j < 4; ++j) {
            int h = hg * 4 + j;
            unsigned short hb = bf16_rtne(zs[j]);
            float hf = __uint_as_float((unsigned)hb << 16);
            u[h] = hb;
            u[32 + h] = bf16_rtne(zs[j] - hf);
        }
    }

    unsigned short* dst = Zhl + ((size_t)row << 6);
    #pragma unroll
    for (int i = 0; i < 8; ++i)
        reinterpret_cast<uint4*>(dst)[i] = *reinterpret_cast<const uint4*>(&u[i * 8]);
}

// Common geometry (pair-sweep kernels):
//  grid (16 n-blocks, 2 m-splits, 32 b); block 256 = 4 waves; wave owns 16 n (B operand, regs).
//  m-window 512 = 4 chunks of 128 rows x 128B (hi+lo) in DOUBLE-BUFFERED LDS,
//  swizzle: slot (c*128 + (row^c)) holds qword c of row  -> 2-way bank max on read.
//  Pipeline (T3 minimal 2-phase + T14 split): issue next chunk's global loads to regs,
//  compute current chunk (hides latency), ds_write regs to idle buffer, ONE barrier/chunk.
//  MFMA 16x16x32 bf16, A = m-tile (LDS), B = n-frag (regs), 3x: mh*nh + mh*nl + ml*nh.
//  C layout: lane holds n = n0w + (lane&15), m = mt*16 + (lane>>4)*4 + k (4 consecutive m).

#define LOAD_N_FRAGS()                                                                   \
    const unsigned short* nrow_ = Zhl + (((size_t)b * NN + n0w + r15) << 6) + (g << 3);  \
    short8 nh = *reinterpret_cast<const short8*>(nrow_);                                 \
    short8 nl = *reinterpret_cast<const short8*>(nrow_ + 32);

#define STAGE_LOAD(m0)                                                                   \
    _Pragma("unroll")                                                                    \
    for (int k_ = 0; k_ < 4; ++k_) {                                                     \
        int s_ = k_ * 256 + t;                                                           \
        int c_ = s_ >> 7, rr_ = s_ & 127;                                                \
        st[k_] = *reinterpret_cast<const uint4*>(                                        \
            Zhl + (((size_t)b * NN + (m0) + (rr_ ^ c_)) << 6) + (c_ << 3));              \
    }

#define STAGE_WRITE(bufp)                                                                \
    _Pragma("unroll")                                                                    \
    for (int k_ = 0; k_ < 4; ++k_) {                                                     \
        int s_ = k_ * 256 + t;                                                           \
        *reinterpret_cast<uint4*>((bufp) + s_ * 8) = st[k_];                             \
    }

#define MFMA_TILE(bufp, mt)                                                              \
    int roff = (mt) * 16 + r15;                                                          \
    short8 mh = *reinterpret_cast<const short8*>(&(bufp)[((g << 7) + (roff ^ g)) << 3]); \
    short8 ml = *reinterpret_cast<const short8*>(                                        \
        &(bufp)[(((g + 4) << 7) + (roff ^ (g + 4))) << 3]);                              \
    floatx4 acc = {0.f, 0.f, 0.f, 0.f};                                                  \
    acc = __builtin_amdgcn_mfma_f32_16x16x32_bf16(mh, nh, acc, 0, 0, 0);                 \
    acc = __builtin_amdgcn_mfma_f32_16x16x32_bf16(mh, nl, acc, 0, 0, 0);                 \
    acc = __builtin_amdgcn_mfma_f32_16x16x32_bf16(ml, nh, acc, 0, 0, 0);

// ---------------- kernel 2: partial row sums  ps[ms][b][n] = sum_{m in window} exp2(a) ----
__global__ __launch_bounds__(256) void k_rowsum(
        const unsigned short* __restrict__ Zhl, float* __restrict__ ps) {
    __shared__ unsigned short Bs[2][128 * 64];
    int t = threadIdx.x, lane = t & 63;
    int r15 = lane & 15, g = lane >> 4;
    int b = blockIdx.z;
    int n0w = blockIdx.x * 64 + (t >> 6) * 16;
    int mbase = blockIdx.y * 512;

    LOAD_N_FRAGS();

    uint4 st[4];
    STAGE_LOAD(mbase);
    STAGE_WRITE(&Bs[0][0]);
    __syncthreads();

    float s = 0.f;
    int cur = 0;
    #pragma unroll
    for (int ch = 0; ch < 4; ++ch) {
        if (ch < 3) STAGE_LOAD(mbase + (ch + 1) * 128);
        const unsigned short* bufp = &Bs[cur][0];
        #pragma unroll
        for (int mt = 0; mt < 8; ++mt) {
            MFMA_TILE(bufp, mt);
            s += __builtin_amdgcn_exp2f(acc[0]) + __builtin_amdgcn_exp2f(acc[1])
               + __builtin_amdgcn_exp2f(acc[2]) + __builtin_amdgcn_exp2f(acc[3]);
        }
        if (ch < 3) { unsigned short* wp = &Bs[cur ^ 1][0]; STAGE_WRITE(wp); }
        __syncthreads();
        cur ^= 1;
    }

    s += __shfl_xor(s, 16, 64);
    s += __shfl_xor(s, 32, 64);
    if (g == 0)
        ps[((size_t)blockIdx.y * BB + b) * NN + n0w + r15] = s;
}

// ---------------- kernel 2b: rinv = 1 / (ps0 + ps1) ----------------
__global__ void k_sfin(const float* __restrict__ ps, float* __restrict__ rinv) {
    int i = blockIdx.x * 256 + threadIdx.x;
    rinv[i] = 1.0f / (ps[i] + ps[32768 + i]);
}

// ---------------- kernel 3: partial col sums  pc[ms][b][n] = sum_m exp2(a)*rinv_m --------
__global__ __launch_bounds__(256) void k_colsum(
        const unsigned short* __restrict__ Zhl, const float* __restrict__ rinv,
        float* __restrict__ pc) {
    __shared__ unsigned short Bs[2][128 * 64];
    int t = threadIdx.x, lane = t & 63;
    int r15 = lane & 15, g = lane >> 4;
    int b = blockIdx.z;
    int n0w = blockIdx.x * 64 + (t >> 6) * 16;
    int mbase = blockIdx.y * 512;

    LOAD_N_FRAGS();

    uint4 st[4];
    STAGE_LOAD(mbase);
    STAGE_WRITE(&Bs[0][0]);
    __syncthreads();

    float c = 0.f;
    int cur = 0;
    #pragma unroll
    for (int ch = 0; ch < 4; ++ch) {
        if (ch < 3) STAGE_LOAD(mbase + (ch + 1) * 128);
        const unsigned short* bufp = &Bs[cur][0];
        #pragma unroll
        for (int mt = 0; mt < 8; ++mt) {
            MFMA_TILE(bufp, mt);
            float4 rm4 = *reinterpret_cast<const float4*>(
                &rinv[(size_t)b * NN + mbase + ch * 128 + mt * 16 + g * 4]);
            c += __builtin_amdgcn_exp2f(acc[0]) * rm4.x + __builtin_amdgcn_exp2f(acc[1]) * rm4.y
               + __builtin_amdgcn_exp2f(acc[2]) * rm4.z + __builtin_amdgcn_exp2f(acc[3]) * rm4.w;
        }
        if (ch < 3) { unsigned short* wp = &Bs[cur ^ 1][0]; STAGE_WRITE(wp); }
        __syncthreads();
        cur ^= 1;
    }

    c += __shfl_xor(c, 16, 64);
    c += __shfl_xor(c, 32, 64);
    if (g == 0)
        pc[((size_t)blockIdx.y * BB + b) * NN + n0w + r15] = c;
}

// ---------------- kernel 3b: dinv = rsqrt(1.5 + 0.5 * (pc0 + pc1)) ----------------
__global__ void k_cfin(const float* __restrict__ pc, float* __restrict__ dinv) {
    int i = blockIdx.x * 256 + threadIdx.x;
    dinv[i] = rsqrtf(1.5f + 0.5f * (pc[i] + pc[32768 + i]));
}

// ---------------- kernel 4: out = (exp2(a)*0.5*(rinv_n + rinv_m) + diag) * dvn * dvm -----
__global__ __launch_bounds__(256) void k_out(
        const unsigned short* __restrict__ Zhl, const float* __restrict__ rinv,
        const float* __restrict__ dinv, float* __restrict__ out) {
    __shared__ unsigned short Bs[2][128 * 64];
    int t = threadIdx.x, lane = t & 63;
    int r15 = lane & 15, g = lane >> 4;
    int b = blockIdx.z;
    int n0w = blockIdx.x * 64 + (t >> 6) * 16;
    int mbase = blockIdx.y * 512;

    int n = n0w + r15;
    float en  = 0.5f * rinv[(size_t)b * NN + n];
    float dvn = dinv[(size_t)b * NN + n];

    LOAD_N_FRAGS();

    uint4 st[4];
    STAGE_LOAD(mbase);
    STAGE_WRITE(&Bs[0][0]);
    __syncthreads();

    float* orow = out + ((size_t)b * NN + n) * NN;

    int cur = 0;
    #pragma unroll
    for (int ch = 0; ch < 4; ++ch) {
        if (ch < 3) STAGE_LOAD(mbase + (ch + 1) * 128);
        const unsigned short* bufp = &Bs[cur][0];
        #pragma unroll
        for (int mt = 0; mt < 8; ++mt) {
            MFMA_TILE(bufp, mt);
            int mg = mbase + ch * 128 + mt * 16 + g * 4;
            float4 rm4 = *reinterpret_cast<const float4*>(&rinv[(size_t)b * NN + mg]);
            float4 dv4 = *reinterpret_cast<const float4*>(&dinv[(size_t)b * NN + mg]);
            float4 o;
            float w0 = dvn * dv4.x, w1 = dvn * dv4.y, w2 = dvn * dv4.z, w3 = dvn * dv4.w;
            o.x = __builtin_amdgcn_exp2f(acc[0]) * (en + 0.5f * rm4.x) * w0;
            o.y = __builtin_amdgcn_exp2f(acc[1]) * (en + 0.5f * rm4.y) * w1;
            o.z = __builtin_amdgcn_exp2f(acc[2]) * (en + 0.5f * rm4.z) * w2;
            o.w = __builtin_amdgcn_exp2f(acc[3]) * (en + 0.5f * rm4.w) * w3;
            if (n == mg + 0) o.x += w0;
            if (n == mg + 1) o.y += w1;
            if (n == mg + 2) o.z += w2;
            if (n == mg + 3) o.w += w3;
            *reinterpret_cast<float4*>(orow + mg) = o;
        }
        if (ch < 3) { unsigned short* wp = &Bs[cur ^ 1][0]; STAGE_WRITE(wp); }
        __syncthreads();
        cur ^= 1;
    }
}

extern "C" void kernel_launch(void* const* d_in, const int* in_sizes, int n_in,
                              void* d_out, int out_size, void* d_ws, size_t ws_size,
                              hipStream_t stream) {
    const float* xt   = (const float*)d_in[0];
    const float* W    = (const float*)d_in[1];
    const float* bias = (const float*)d_in[2];
    float* out = (float*)d_out;
    float* ws  = (float*)d_ws;

    unsigned short* Zhl = (unsigned short*)ws;          // 32*1024*64 u16 = 1,048,576 floats
    float* ps   = ws + 1048576;                         // [2][32][1024] = 65536
    float* pc   = ws + 1048576 + 65536;                 // [2][32][1024] = 65536
    float* rinv = ws + 1048576 + 131072;                // 32768
    float* dinv = ws + 1048576 + 163840;                // 32768

    k_z<<<dim3(BB * NN / 256), dim3(256), 0, stream>>>(xt, W, bias, Zhl);
    k_rowsum<<<dim3(16, 2, BB), dim3(256), 0, stream>>>(Zhl, ps);
    k_sfin<<<dim3(128), dim3(256), 0, stream>>>(ps, rinv);
    k_colsum<<<dim3(16, 2, BB), dim3(256), 0, stream>>>(Zhl, rinv, pc);
    k_cfin<<<dim3(128), dim3(256), 0, stream>>>(pc, dinv);
    k_out<<<dim3(16, 2, BB), dim3(256), 0, stream>>>(Zhl, rinv, dinv, out);
}

// Round 10
// 81.931 us; speedup vs baseline: 1.7648x; 1.1851x over previous
//
#include <hip/hip_runtime.h>

#define BB 32
#define NN 1024
#define FIN 64
#define HH 24
#define SQRT_LOG2E 1.2011224087864498f

typedef __attribute__((ext_vector_type(8))) short short8;
typedef __attribute__((ext_vector_type(4))) float floatx4;

static __device__ inline unsigned short bf16_rtne(float f) {
    unsigned u = __float_as_uint(f);
    unsigned r = u + 0x7FFFu + ((u >> 16) & 1u);
    return (unsigned short)(r >> 16);
}

// ---------------- kernel 1: Z = relu(xt@W+b) * SQRT_LOG2E, split hi/lo bf16 ----------------
// Zhl[b][n] = 64 ushorts: [0..23] hi bf16, [24..31] 0, [32..55] lo bf16, [56..63] 0
__global__ void k_z(const float* __restrict__ xt, const float* __restrict__ W,
                    const float* __restrict__ bias, unsigned short* __restrict__ Zhl) {
    __shared__ float Wl[FIN * HH];
    int t = threadIdx.x;
    for (int i = t; i < FIN * HH; i += 256) Wl[i] = W[i];
    __syncthreads();

    int row = blockIdx.x * 256 + t;      // b*N + n

    const float* xr = xt + (size_t)row * FIN;
    float x[FIN];
    #pragma unroll
    for (int k4 = 0; k4 < FIN / 4; ++k4) {
        float4 v = reinterpret_cast<const float4*>(xr)[k4];
        x[4 * k4 + 0] = v.x; x[4 * k4 + 1] = v.y;
        x[4 * k4 + 2] = v.z; x[4 * k4 + 3] = v.w;
    }

    unsigned short u[64];
    #pragma unroll
    for (int i = 0; i < 64; ++i) u[i] = 0;

    #pragma unroll
    for (int hg = 0; hg < HH / 4; ++hg) {
        float4 acc = reinterpret_cast<const float4*>(bias)[hg];
        #pragma unroll
        for (int k = 0; k < FIN; ++k) {
            float4 w = *reinterpret_cast<const float4*>(&Wl[k * HH + hg * 4]);
            acc.x += x[k] * w.x; acc.y += x[k] * w.y;
            acc.z += x[k] * w.z; acc.w += x[k] * w.w;
        }
        float zs[4] = { fmaxf(acc.x, 0.f) * SQRT_LOG2E, fmaxf(acc.y, 0.f) * SQRT_LOG2E,
                        fmaxf(acc.z, 0.f) * SQRT_LOG2E, fmaxf(acc.w, 0.f) * SQRT_LOG2E };
        #pragma unroll
        for (int j = 0; j < 4; ++j) {
            int h = hg * 4 + j;
            unsigned short hb = bf16_rtne(zs[j]);
            float hf = __uint_as_float((unsigned)hb << 16);
            u[h] = hb;
            u[32 + h] = bf16_rtne(zs[j] - hf);
        }
    }

    unsigned short* dst = Zhl + ((size_t)row << 6);
    #pragma unroll
    for (int i = 0; i < 8; ++i)
        reinterpret_cast<uint4*>(dst)[i] = *reinterpret_cast<const uint4*>(&u[i * 8]);
}

// Common geometry (pair-sweep kernels) — R7 frame + 32n/wave register blocking:
//  grid (8 n-blocks, 4 m-splits, 32 b); block 256 = 4 waves; wave owns 32 n
//  (two B-frag sets A/B in regs: nA = bx*128 + w*32 + r15, nB = nA + 16).
//  m-window 256 = 2 LDS chunks of 128 rows x 128B (hi+lo), single-buffered,
//  swizzle: slot (c*128 + (row^c)) holds qword c of row -> 2-way bank max.
//  Per tile: 2 ds_read_b128 feed 6 MFMA (16x16x32 bf16): mh*nhA+mh*nlA+ml*nhA, same for B.
//  C layout: lane holds n = (A|B base) + (lane&15), m = mt*16 + (lane>>4)*4 + k.

#define STAGE_CHUNK(m0)                                                                  \
    for (int i = t; i < 1024; i += 256) {                                                \
        int row_ = i >> 3, c_ = i & 7;                                                   \
        uint4 v_ = *reinterpret_cast<const uint4*>(                                      \
            Zhl + (((size_t)b * NN + (m0) + row_) << 6) + (c_ << 3));                    \
        *reinterpret_cast<uint4*>(&Bs[(((c_ << 7) + (row_ ^ c_)) << 3)]) = v_;           \
    }

#define LOAD_N_FRAGS2()                                                                  \
    const unsigned short* nrowA_ = Zhl + (((size_t)b * NN + nA) << 6) + (g << 3);        \
    short8 nhA = *reinterpret_cast<const short8*>(nrowA_);                               \
    short8 nlA = *reinterpret_cast<const short8*>(nrowA_ + 32);                          \
    const unsigned short* nrowB_ = Zhl + (((size_t)b * NN + nB) << 6) + (g << 3);        \
    short8 nhB = *reinterpret_cast<const short8*>(nrowB_);                               \
    short8 nlB = *reinterpret_cast<const short8*>(nrowB_ + 32);

#define MFMA_TILE2(mt)                                                                   \
    int roff = (mt) * 16 + r15;                                                          \
    short8 mh = *reinterpret_cast<const short8*>(&Bs[((g << 7) + (roff ^ g)) << 3]);     \
    short8 ml = *reinterpret_cast<const short8*>(                                        \
        &Bs[(((g + 4) << 7) + (roff ^ (g + 4))) << 3]);                                  \
    floatx4 accA = {0.f, 0.f, 0.f, 0.f};                                                 \
    accA = __builtin_amdgcn_mfma_f32_16x16x32_bf16(mh, nhA, accA, 0, 0, 0);              \
    accA = __builtin_amdgcn_mfma_f32_16x16x32_bf16(mh, nlA, accA, 0, 0, 0);              \
    accA = __builtin_amdgcn_mfma_f32_16x16x32_bf16(ml, nhA, accA, 0, 0, 0);              \
    floatx4 accB = {0.f, 0.f, 0.f, 0.f};                                                 \
    accB = __builtin_amdgcn_mfma_f32_16x16x32_bf16(mh, nhB, accB, 0, 0, 0);              \
    accB = __builtin_amdgcn_mfma_f32_16x16x32_bf16(mh, nlB, accB, 0, 0, 0);              \
    accB = __builtin_amdgcn_mfma_f32_16x16x32_bf16(ml, nhB, accB, 0, 0, 0);

// ---------------- kernel 2: partial row sums  ps[ms][b][n] = sum_{m in window} exp2(a) ----
__global__ __launch_bounds__(256) void k_rowsum(
        const unsigned short* __restrict__ Zhl, float* __restrict__ ps) {
    __shared__ unsigned short Bs[128 * 64];
    int t = threadIdx.x, lane = t & 63;
    int r15 = lane & 15, g = lane >> 4;
    int b = blockIdx.z;
    int nA = blockIdx.x * 128 + (t >> 6) * 32 + r15;
    int nB = nA + 16;
    int mbase = blockIdx.y * 256;

    LOAD_N_FRAGS2();

    float sA = 0.f, sB = 0.f;

    #pragma unroll
    for (int ch = 0; ch < 2; ++ch) {
        __syncthreads();
        STAGE_CHUNK(mbase + ch * 128);
        __syncthreads();
        #pragma unroll
        for (int mt = 0; mt < 8; ++mt) {
            MFMA_TILE2(mt);
            sA += __builtin_amdgcn_exp2f(accA[0]) + __builtin_amdgcn_exp2f(accA[1])
                + __builtin_amdgcn_exp2f(accA[2]) + __builtin_amdgcn_exp2f(accA[3]);
            sB += __builtin_amdgcn_exp2f(accB[0]) + __builtin_amdgcn_exp2f(accB[1])
                + __builtin_amdgcn_exp2f(accB[2]) + __builtin_amdgcn_exp2f(accB[3]);
        }
    }

    sA += __shfl_xor(sA, 16, 64); sA += __shfl_xor(sA, 32, 64);
    sB += __shfl_xor(sB, 16, 64); sB += __shfl_xor(sB, 32, 64);
    if (g == 0) {
        size_t base = ((size_t)blockIdx.y * BB + b) * NN;
        ps[base + nA] = sA;
        ps[base + nB] = sB;
    }
}

// ---------------- kernel 3: partial col sums  pc[ms][b][n] = sum_m exp2(a)/s_m ----------
__global__ __launch_bounds__(256) void k_colsum(
        const unsigned short* __restrict__ Zhl, const float* __restrict__ ps,
        float* __restrict__ pc) {
    __shared__ unsigned short Bs[128 * 64];
    __shared__ float rmS[256];
    int t = threadIdx.x, lane = t & 63;
    int r15 = lane & 15, g = lane >> 4;
    int b = blockIdx.z;
    int nA = blockIdx.x * 128 + (t >> 6) * 32 + r15;
    int nB = nA + 16;
    int mbase = blockIdx.y * 256;

    // 1/s_m for the m-window (fused former k_sfin)
    {
        size_t o = (size_t)b * NN + mbase + t;
        float sm = ps[o] + ps[32768 + o] + ps[65536 + o] + ps[98304 + o];
        rmS[t] = 1.0f / sm;
    }

    LOAD_N_FRAGS2();

    float cA = 0.f, cB = 0.f;

    #pragma unroll
    for (int ch = 0; ch < 2; ++ch) {
        __syncthreads();
        STAGE_CHUNK(mbase + ch * 128);
        __syncthreads();
        #pragma unroll
        for (int mt = 0; mt < 8; ++mt) {
            MFMA_TILE2(mt);
            float4 rm4 = *reinterpret_cast<const float4*>(&rmS[ch * 128 + mt * 16 + g * 4]);
            cA += __builtin_amdgcn_exp2f(accA[0]) * rm4.x + __builtin_amdgcn_exp2f(accA[1]) * rm4.y
                + __builtin_amdgcn_exp2f(accA[2]) * rm4.z + __builtin_amdgcn_exp2f(accA[3]) * rm4.w;
            cB += __builtin_amdgcn_exp2f(accB[0]) * rm4.x + __builtin_amdgcn_exp2f(accB[1]) * rm4.y
                + __builtin_amdgcn_exp2f(accB[2]) * rm4.z + __builtin_amdgcn_exp2f(accB[3]) * rm4.w;
        }
    }

    cA += __shfl_xor(cA, 16, 64); cA += __shfl_xor(cA, 32, 64);
    cB += __shfl_xor(cB, 16, 64); cB += __shfl_xor(cB, 32, 64);
    if (g == 0) {
        size_t base = ((size_t)blockIdx.y * BB + b) * NN;
        pc[base + nA] = cA;
        pc[base + nB] = cB;
    }
}

// ---------------- kernel 4: out = (exp2(a)*0.5*(rinv_n + rinv_m) + diag) * dvn * dvm -----
__global__ __launch_bounds__(256) void k_out(
        const unsigned short* __restrict__ Zhl, const float* __restrict__ ps,
        const float* __restrict__ pc, float* __restrict__ out) {
    __shared__ unsigned short Bs[128 * 64];
    __shared__ float emS[256], dvmS[256];
    int t = threadIdx.x, lane = t & 63;
    int r15 = lane & 15, g = lane >> 4;
    int b = blockIdx.z;
    int nA = blockIdx.x * 128 + (t >> 6) * 32 + r15;
    int nB = nA + 16;
    int mbase = blockIdx.y * 256;

    // m-window stats (fused former k_sfin/k_cfin): em = 0.5/s_m, dvm = rsqrt(1.5+0.5*c_m)
    {
        size_t o = (size_t)b * NN + mbase + t;
        float sm = ps[o] + ps[32768 + o] + ps[65536 + o] + ps[98304 + o];
        float cm = pc[o] + pc[32768 + o] + pc[65536 + o] + pc[98304 + o];
        emS[t]  = 0.5f / sm;
        dvmS[t] = rsqrtf(1.5f + 0.5f * cm);
    }

    // per-lane n stats
    float enA, dvnA, enB, dvnB;
    {
        size_t oA = (size_t)b * NN + nA;
        float snA = ps[oA] + ps[32768 + oA] + ps[65536 + oA] + ps[98304 + oA];
        float cnA = pc[oA] + pc[32768 + oA] + pc[65536 + oA] + pc[98304 + oA];
        enA  = 0.5f / snA;
        dvnA = rsqrtf(1.5f + 0.5f * cnA);
        size_t oB = oA + 16;
        float snB = ps[oB] + ps[32768 + oB] + ps[65536 + oB] + ps[98304 + oB];
        float cnB = pc[oB] + pc[32768 + oB] + pc[65536 + oB] + pc[98304 + oB];
        enB  = 0.5f / snB;
        dvnB = rsqrtf(1.5f + 0.5f * cnB);
    }

    LOAD_N_FRAGS2();

    float* orowA = out + ((size_t)b * NN + nA) * NN;
    float* orowB = out + ((size_t)b * NN + nB) * NN;

    #pragma unroll
    for (int ch = 0; ch < 2; ++ch) {
        __syncthreads();
        STAGE_CHUNK(mbase + ch * 128);
        __syncthreads();
        #pragma unroll
        for (int mt = 0; mt < 8; ++mt) {
            MFMA_TILE2(mt);
            int mq = ch * 128 + mt * 16 + g * 4;
            float4 em4 = *reinterpret_cast<const float4*>(&emS[mq]);
            float4 dv4 = *reinterpret_cast<const float4*>(&dvmS[mq]);
            int mg = mbase + mq;
            {
                float4 o;
                float w0 = dvnA * dv4.x, w1 = dvnA * dv4.y, w2 = dvnA * dv4.z, w3 = dvnA * dv4.w;
                o.x = __builtin_amdgcn_exp2f(accA[0]) * (enA + em4.x) * w0;
                o.y = __builtin_amdgcn_exp2f(accA[1]) * (enA + em4.y) * w1;
                o.z = __builtin_amdgcn_exp2f(accA[2]) * (enA + em4.z) * w2;
                o.w = __builtin_amdgcn_exp2f(accA[3]) * (enA + em4.w) * w3;
                if (nA == mg + 0) o.x += w0;
                if (nA == mg + 1) o.y += w1;
                if (nA == mg + 2) o.z += w2;
                if (nA == mg + 3) o.w += w3;
                *reinterpret_cast<float4*>(orowA + mg) = o;
            }
            {
                float4 o;
                float w0 = dvnB * dv4.x, w1 = dvnB * dv4.y, w2 = dvnB * dv4.z, w3 = dvnB * dv4.w;
                o.x = __builtin_amdgcn_exp2f(accB[0]) * (enB + em4.x) * w0;
                o.y = __builtin_amdgcn_exp2f(accB[1]) * (enB + em4.y) * w1;
                o.z = __builtin_amdgcn_exp2f(accB[2]) * (enB + em4.z) * w2;
                o.w = __builtin_amdgcn_exp2f(accB[3]) * (enB + em4.w) * w3;
                if (nB == mg + 0) o.x += w0;
                if (nB == mg + 1) o.y += w1;
                if (nB == mg + 2) o.z += w2;
                if (nB == mg + 3) o.w += w3;
                *reinterpret_cast<float4*>(orowB + mg) = o;
            }
        }
    }
}

extern "C" void kernel_launch(void* const* d_in, const int* in_sizes, int n_in,
                              void* d_out, int out_size, void* d_ws, size_t ws_size,
                              hipStream_t stream) {
    const float* xt   = (const float*)d_in[0];
    const float* W    = (const float*)d_in[1];
    const float* bias = (const float*)d_in[2];
    float* out = (float*)d_out;
    float* ws  = (float*)d_ws;

    unsigned short* Zhl = (unsigned short*)ws;          // 32*1024*64 u16 = 1,048,576 floats
    float* ps = ws + 1048576;                           // [4][32][1024] = 131072
    float* pc = ws + 1048576 + 131072;                  // [4][32][1024] = 131072

    k_z<<<dim3(BB * NN / 256), dim3(256), 0, stream>>>(xt, W, bias, Zhl);
    k_rowsum<<<dim3(8, 4, BB), dim3(256), 0, stream>>>(Zhl, ps);
    k_colsum<<<dim3(8, 4, BB), dim3(256), 0, stream>>>(Zhl, ps, pc);
    k_out<<<dim3(8, 4, BB), dim3(256), 0, stream>>>(Zhl, ps, pc, out);
}